// Round 1
// baseline (376.290 us; speedup 1.0000x reference)
//
#include <hip/hip_runtime.h>

// ---------- problem constants ----------
#define CDIM   768
#define NSEQ   196
#define NVIEW  5
#define BN_TOT 6272       // B*N
#define SLAB   4816896    // BN_TOT*CDIM
#define WSLAB  589824     // CDIM*CDIM

typedef __attribute__((ext_vector_type(8))) short short8;  // 8 bf16 (4 VGPRs)
typedef __attribute__((ext_vector_type(4))) float f32x4;

// ---------- helpers ----------
__device__ __forceinline__ float bf_lo(unsigned u) { return __uint_as_float(u << 16); }
__device__ __forceinline__ float bf_hi(unsigned u) { return __uint_as_float(u & 0xffff0000u); }
__device__ __forceinline__ unsigned short f2bf(float f) {
  unsigned u = __float_as_uint(f);
  return (unsigned short)((u + 0x7fffu + ((u >> 16) & 1u)) >> 16);  // RNE
}
__device__ __forceinline__ unsigned pack2(float f0, float f1) {
  return (unsigned)f2bf(f0) | ((unsigned)f2bf(f1) << 16);
}
__device__ __forceinline__ float ftanh(float x) {
  x = fminf(fmaxf(x, -10.f), 10.f);
  float e = __expf(2.f * x);
  return (e - 1.f) / (e + 1.f);
}
__device__ __forceinline__ void async_cp16(const void* g, void* l) {
  __builtin_amdgcn_global_load_lds((const __attribute__((address_space(1))) unsigned*)g,
                                   (__attribute__((address_space(3))) unsigned*)l, 16, 0, 0);
}

// ---------- weight transpose fp32 -> bf16: 7 matrices of 768x768 ----------
__global__ __launch_bounds__(256) void k_tr(const float* __restrict__ wv,
                                            const float* __restrict__ w1,
                                            unsigned short* __restrict__ wvT,
                                            unsigned short* __restrict__ w1aT,
                                            unsigned short* __restrict__ w1bT) {
  __shared__ float tile[32][33];
  const int m = blockIdx.z;
  const float* src;
  unsigned short* dst;
  if (m < NVIEW)      { src = wv + (size_t)m * WSLAB; dst = wvT + (size_t)m * WSLAB; }
  else if (m == NVIEW){ src = w1;                     dst = w1aT; }
  else                { src = w1 + WSLAB;             dst = w1bT; }
  const int tx = threadIdx.x, ty = threadIdx.y;
  const int x0 = blockIdx.x * 32, y0 = blockIdx.y * 32;
#pragma unroll
  for (int i = 0; i < 4; ++i)
    tile[ty + i * 8][tx] = src[(size_t)(y0 + ty + i * 8) * CDIM + x0 + tx];
  __syncthreads();
#pragma unroll
  for (int i = 0; i < 4; ++i)
    dst[(size_t)(x0 + ty + i * 8) * CDIM + y0 + tx] = f2bf(tile[tx][ty + i * 8]);
}

// ---------- single pass over x: xb[v][bn][c] = bf16(x), cb = mean over v ----------
__global__ __launch_bounds__(192) void k_cvt_mean(const float* __restrict__ x,
                                                  unsigned short* __restrict__ xb,
                                                  unsigned short* __restrict__ cb) {
  const int bn = blockIdx.x;
  const int b = bn / NSEQ, n = bn % NSEQ;
  const int h = threadIdx.x * 4;
  const float* xp = x + ((size_t)(b * NVIEW) * NSEQ + n) * CDIM + h;
  float s0 = 0, s1 = 0, s2 = 0, s3 = 0;
#pragma unroll
  for (int v = 0; v < NVIEW; ++v) {
    float4 p = *(const float4*)(xp + (size_t)v * (NSEQ * CDIM));
    s0 += p.x; s1 += p.y; s2 += p.z; s3 += p.w;
    uint2 q; q.x = pack2(p.x, p.y); q.y = pack2(p.z, p.w);
    *(uint2*)(xb + ((size_t)v * BN_TOT + bn) * CDIM + h) = q;
  }
  uint2 o;
  o.x = pack2(s0 * 0.2f, s1 * 0.2f);
  o.y = pack2(s2 * 0.2f, s3 * 0.2f);
  *(uint2*)(cb + (size_t)bn * CDIM + h) = o;
}

// ---------- 256x256-tile 8-wave MFMA GEMM, 4-deep LDS ring, counted vmcnt ----------
// Bt layout [Nout, K]. 8 waves as 2(M)x4(N); per-wave output 128x64.
// K-tile = BK=32 (A 16KB + B 16KB in LDS); 4 ring buffers = 128 KiB.
// Per K-tile: 2 phases (qm=0/1), 16 MFMA each, between double barriers.
// Stage rhythm: during K-tile kt, issue K-tile kt+3 (A-rounds in phase 0,
// B-rounds in phase 1) into ring slot (kt+3)&3 = (kt-1)&3, whose last
// ds_reads completed >=1 barrier earlier (race-free ledger).
// Steady-state wait: vmcnt(8) once per K-tile (tiles kt+2,kt+3 in flight);
// tail drains 8->4->0. LDS XOR-swizzle: logical k-chunk ^= (row>>1)&3,
// applied as pre-swizzled GLOBAL source (linear global_load_lds dest) and
// identically on the ds_read address (involution, both-sides).
// M=6272 = 24.5 x 256: tile mt=24 half-OOB; boundary == wm split, so the
// wm=128 wave-group just skips its stores. OOB A rows read valid workspace
// and only feed never-stored acc rows (MFMA rows are independent).
// MODE 0 (11 slabs): z<5 proj_v=xb_v@wvT_v ; z in[5,10) xw1_v=xb_v@w1aT ;
//   z==10 cw1=cb@w1bT.   MODE 1 (5 slabs): pw1b_z = projb_z @ w1bT.
template <int MODE>
__global__ __launch_bounds__(512, 2) void gemm256(const unsigned short* __restrict__ P0,
                                                  const unsigned short* __restrict__ P1,
                                                  const unsigned short* __restrict__ P2,
                                                  const unsigned short* __restrict__ P3,
                                                  const unsigned short* __restrict__ P4,
                                                  unsigned short* __restrict__ Q0,
                                                  unsigned short* __restrict__ Q1,
                                                  unsigned short* __restrict__ Q2) {
  extern __shared__ unsigned short ldsb[];   // 4 bufs x (8192 A + 8192 B) shorts = 128 KiB
  constexpr int NWG = (MODE == 0) ? 825 : 375;   // 11*75 / 5*75 works, grid == NWG
  constexpr int NKT = CDIM / 32;                 // 24 K-tiles
  // bijective XCD swizzle (m204 form): each XCD gets a contiguous wgid chunk
  const int orig = blockIdx.x;
  const int q = NWG >> 3, r = NWG & 7, xcd = orig & 7, slot = orig >> 3;
  const int wgid = (xcd < r ? xcd * (q + 1) : r * (q + 1) + (xcd - r) * q) + slot;
  const int nt = wgid % 3;
  const int wq = wgid / 3;
  const int mt = wq % 25, z = wq / 25;

  const unsigned short *A, *Bt;
  unsigned short* C;
  if (MODE == 0) {
    if (z == 10)    { A = P1; Bt = P4; C = Q2; }
    else if (z < 5) { A = P0 + (size_t)z * SLAB;       Bt = P2 + (size_t)z * WSLAB; C = Q0 + (size_t)z * SLAB; }
    else            { A = P0 + (size_t)(z - 5) * SLAB; Bt = P3;                     C = Q1 + (size_t)(z - 5) * SLAB; }
  } else {
    A = P0 + (size_t)z * SLAB; Bt = P4; C = Q0 + (size_t)z * SLAB;
  }

  const int t = threadIdx.x, w = t >> 6, lane = t & 63, lr = lane & 15, lq = lane >> 4;
  const int wm = (w >> 2) << 7;   // 0 / 128
  const int wn = (w & 3) << 6;    // 0 / 64 / 128 / 192

  // ---- staging source (pre-swizzled k-chunk so linear LDS dest ends up swizzled) ----
  // thread t covers row (t>>2) (+128 for round 1); swizzle s(row) = (row>>1)&3 = (t>>3)&3
  const int kc = (((t & 3) ^ ((t >> 3) & 3)) << 3);            // source k-chunk (shorts)
  const unsigned short* gA = A  + (size_t)(mt * 256 + (t >> 2)) * CDIM + kc;
  const unsigned short* gB = Bt + (size_t)(nt * 256 + (t >> 2)) * CDIM + kc;

  // ---- ds_read addressing (same involution: chunk = lq ^ ((row>>1)&3) = lq ^ ((lr>>1)&3)) ----
  const int kch = ((lq ^ ((lr >> 1) & 3)) << 3);
  const int raBase = (wm + lr) * 32 + kch;           // A region, + fi*512 per 16-row frag
  const int rbBase = 8192 + (wn + lr) * 32 + kch;    // B region, + j*512 per 16-col frag

  // wave-uniform LDS dest base for global_load_lds (HW adds lane*16B)
#define STAGE_A(st) { const unsigned short* s_ = gA + (st) * 32;                      \
    unsigned short* d_ = ldsb + (((st) & 3) << 14) + (w << 9);                        \
    async_cp16(s_, d_); async_cp16(s_ + (size_t)128 * CDIM, d_ + 4096); }
#define STAGE_B(st) { const unsigned short* s_ = gB + (st) * 32;                      \
    unsigned short* d_ = ldsb + (((st) & 3) << 14) + 8192 + (w << 9);                 \
    async_cp16(s_, d_); async_cp16(s_ + (size_t)128 * CDIM, d_ + 4096); }

  f32x4 acc[8][4] = {};

  // ---- prologue: stage K-tiles 0,1,2 (12 loads/thread); wait tile 0 (8 left in flight) ----
  STAGE_A(0); STAGE_B(0);
  STAGE_A(1); STAGE_B(1);
  STAGE_A(2); STAGE_B(2);
  asm volatile("s_waitcnt vmcnt(8)");
  __builtin_amdgcn_s_barrier();

  for (int kt = 0; kt < NKT; ++kt) {
    const unsigned short* bufp = ldsb + ((kt & 3) << 14);
    short8 af[4], bf[4];
    // ================= phase qm = 0 =================
#pragma unroll
    for (int j = 0; j < 4; ++j) bf[j] = *(const short8*)(bufp + rbBase + (j << 9));
#pragma unroll
    for (int i = 0; i < 4; ++i) af[i] = *(const short8*)(bufp + raBase + (i << 9));
    if (kt + 3 < NKT) STAGE_A(kt + 3);            // -> slot (kt-1)&3, A region freed last K-tile
    __builtin_amdgcn_s_barrier();
    asm volatile("s_waitcnt lgkmcnt(0)");
    __builtin_amdgcn_s_setprio(1);
#pragma unroll
    for (int i = 0; i < 4; ++i)
#pragma unroll
      for (int j = 0; j < 4; ++j)
        acc[i][j] = __builtin_amdgcn_mfma_f32_16x16x32_bf16(af[i], bf[j], acc[i][j], 0, 0, 0);
    __builtin_amdgcn_s_setprio(0);
    __builtin_amdgcn_s_barrier();
    // ================= phase qm = 1 =================
#pragma unroll
    for (int i = 0; i < 4; ++i) af[i] = *(const short8*)(bufp + raBase + 2048 + (i << 9));
    if (kt + 3 < NKT) STAGE_B(kt + 3);            // B region of same slot, freed even earlier
    __builtin_amdgcn_s_barrier();
    asm volatile("s_waitcnt lgkmcnt(0)");
    __builtin_amdgcn_s_setprio(1);
#pragma unroll
    for (int i = 0; i < 4; ++i)
#pragma unroll
      for (int j = 0; j < 4; ++j)
        acc[4 + i][j] = __builtin_amdgcn_mfma_f32_16x16x32_bf16(af[i], bf[j], acc[4 + i][j], 0, 0, 0);
    __builtin_amdgcn_s_setprio(0);
    // counted wait for NEXT K-tile's data: never 0 in steady state
    if (kt < NKT - 3)       { asm volatile("s_waitcnt vmcnt(8)"); }
    else if (kt == NKT - 3) { asm volatile("s_waitcnt vmcnt(4)"); }
    else if (kt == NKT - 2) { asm volatile("s_waitcnt vmcnt(0)"); }
    __builtin_amdgcn_s_barrier();
  }
#undef STAGE_A
#undef STAGE_B

  // ---- epilogue: M-tail (6272 = 24.5*256) aligns with wm split -> whole-wave guard ----
  if (mt * 256 + wm < BN_TOT) {
    const size_t row0 = (size_t)(mt * 256 + wm + lq * 4);
    const int col0 = nt * 256 + wn + lr;
#pragma unroll
    for (int fi = 0; fi < 8; ++fi)
#pragma unroll
      for (int j = 0; j < 4; ++j) {
        unsigned short* cp = C + (row0 + fi * 16) * CDIM + col0 + j * 16;
#pragma unroll
        for (int rr = 0; rr < 4; ++rr)
          cp[(size_t)rr * CDIM] = f2bf(acc[fi][j][rr]);
      }
  }
}

// ---------- fully fused routing loop: 3x (scores -> softmax -> weighted sum), pointwise in bn ----------
__global__ __launch_bounds__(192) void k_iter3(const unsigned short* __restrict__ xw1b,
                                               const unsigned short* __restrict__ cw1,
                                               const unsigned short* __restrict__ pw1b,
                                               const unsigned short* __restrict__ projb,
                                               const float* __restrict__ b1,
                                               const float* __restrict__ w2,
                                               float* __restrict__ outc,
                                               float* __restrict__ outr) {
  __shared__ float red[3][NVIEW];
  __shared__ float aa[NVIEW];
  const int bn = blockIdx.x, t = threadIdx.x, wid = t >> 6, lane = t & 63;
  const int h = t * 4;
  const float4 bv = *(const float4*)(b1 + h);
  const float4 wv = *(const float4*)(w2 + h);
  float cw[4];
  { uint2 c = *(const uint2*)(cw1 + (size_t)bn * CDIM + h);
    cw[0] = bf_lo(c.x); cw[1] = bf_hi(c.x); cw[2] = bf_lo(c.y); cw[3] = bf_hi(c.y); }
  float xw[NVIEW][4], pf[NVIEW][4];
#pragma unroll
  for (int v = 0; v < NVIEW; ++v) {
    uint2 q = *(const uint2*)(xw1b + ((size_t)v * BN_TOT + bn) * CDIM + h);
    xw[v][0] = bf_lo(q.x) + bv.x; xw[v][1] = bf_hi(q.x) + bv.y;
    xw[v][2] = bf_lo(q.y) + bv.z; xw[v][3] = bf_hi(q.y) + bv.w;
    uint2 p = *(const uint2*)(pw1b + ((size_t)v * BN_TOT + bn) * CDIM + h);
    pf[v][0] = bf_lo(p.x); pf[v][1] = bf_hi(p.x);
    pf[v][2] = bf_lo(p.y); pf[v][3] = bf_hi(p.y);
  }
  for (int it = 0; it < 3; ++it) {
    float part[NVIEW];
#pragma unroll
    for (int v = 0; v < NVIEW; ++v) {
      float p;
      p = wv.x * ftanh(xw[v][0] + cw[0]);
      p = fmaf(wv.y, ftanh(xw[v][1] + cw[1]), p);
      p = fmaf(wv.z, ftanh(xw[v][2] + cw[2]), p);
      p = fmaf(wv.w, ftanh(xw[v][3] + cw[3]), p);
      part[v] = p;
    }
#pragma unroll
    for (int off = 32; off > 0; off >>= 1)
#pragma unroll
      for (int v = 0; v < NVIEW; ++v) part[v] += __shfl_down(part[v], off);
    if (lane == 0)
#pragma unroll
      for (int v = 0; v < NVIEW; ++v) red[wid][v] = part[v];
    __syncthreads();
    if (t == 0) {
      float s[NVIEW];
#pragma unroll
      for (int v = 0; v < NVIEW; ++v) s[v] = red[0][v] + red[1][v] + red[2][v];
      float m = s[0];
#pragma unroll
      for (int v = 1; v < NVIEW; ++v) m = fmaxf(m, s[v]);
      float a[NVIEW], sum = 0.f;
#pragma unroll
      for (int v = 0; v < NVIEW; ++v) { a[v] = __expf(s[v] - m); sum += a[v]; }
      const float inv = 1.f / sum;
#pragma unroll
      for (int v = 0; v < NVIEW; ++v) { a[v] *= inv; aa[v] = a[v]; }
      if (it == 2) {
        float ent = 0.f;
#pragma unroll
        for (int v = 0; v < NVIEW; ++v) ent -= a[v] * logf(a[v] + 1e-8f);
        outr[bn] = 1.f - ent * 0.6213349345596119f;  // 1/ln(5)
      }
    }
    __syncthreads();
    if (it < 2) {
      float n0 = 0, n1 = 0, n2 = 0, n3 = 0;
#pragma unroll
      for (int v = 0; v < NVIEW; ++v) {
        const float av = aa[v];
        n0 = fmaf(av, pf[v][0], n0); n1 = fmaf(av, pf[v][1], n1);
        n2 = fmaf(av, pf[v][2], n2); n3 = fmaf(av, pf[v][3], n3);
      }
      cw[0] = n0; cw[1] = n1; cw[2] = n2; cw[3] = n3;
    } else {
      float r0 = 0, r1 = 0, r2 = 0, r3 = 0;
#pragma unroll
      for (int v = 0; v < NVIEW; ++v) {
        const float av = aa[v];
        uint2 p = *(const uint2*)(projb + ((size_t)v * BN_TOT + bn) * CDIM + h);
        r0 = fmaf(av, bf_lo(p.x), r0); r1 = fmaf(av, bf_hi(p.x), r1);
        r2 = fmaf(av, bf_lo(p.y), r2); r3 = fmaf(av, bf_hi(p.y), r3);
      }
      float4 of; of.x = r0; of.y = r1; of.z = r2; of.w = r3;
      *(float4*)(outc + (size_t)bn * CDIM + h) = of;
    }
  }
}

extern "C" void kernel_launch(void* const* d_in, const int* in_sizes, int n_in,
                              void* d_out, int out_size, void* d_ws, size_t ws_size,
                              hipStream_t stream) {
  (void)in_sizes; (void)n_in; (void)out_size; (void)ws_size;
  const float* x  = (const float*)d_in[0];   // [B,V,N,C] fp32
  const float* wv = (const float*)d_in[1];   // [V,C,C]
  const float* w1 = (const float*)d_in[2];   // [2C,H]
  const float* b1 = (const float*)d_in[3];   // [H]
  const float* w2 = (const float*)d_in[4];   // [H,1]
  // d_in[5] = b2: uniform shift over views -> softmax-invariant, unused.

  // workspace: 86,016,000 ushorts = 172 MB (known-safe; 232 MB overflowed in round 6)
  unsigned short* ws   = (unsigned short*)d_ws;
  unsigned short* wvT  = ws;                             //  2,949,120  [V][d][c]
  unsigned short* w1aT = ws + 2949120;                   //    589,824
  unsigned short* w1bT = ws + 3538944;                   //    589,824
  unsigned short* xb   = ws + 4128768;                   // 24,084,480  [V,BN,C]; dead after GEMM A
  unsigned short* pw1b = ws + 4128768;                   //   (aliased onto xb)
  unsigned short* projb= ws + 28213248;                  // 24,084,480
  unsigned short* xw1b = ws + 52297728;                  // 24,084,480
  unsigned short* cb   = ws + 76382208;                  //  4,816,896
  unsigned short* cw1  = ws + 81199104;                  //  4,816,896  (end: 86,016,000)

  float* outc = (float*)d_out;                           // c [B,N,C] fp32
  float* outr = outc + SLAB;                             // r [B,N]   fp32

  k_tr<<<dim3(24, 24, 7), dim3(32, 8), 0, stream>>>(wv, w1, wvT, w1aT, w1bT);
  k_cvt_mean<<<BN_TOT, 192, 0, stream>>>(x, xb, cb);
  // GEMM A: proj_v = xb_v @ wv_v ; xw1_v = xb_v @ w1a ; cw1 = cb @ w1b
  // 11 slabs x 25 M-tiles x 3 N-tiles = 825 blocks of 512 thr, 128 KiB dyn LDS
  gemm256<0><<<825, 512, 131072, stream>>>(xb, cb, wvT, w1aT, w1bT, projb, xw1b, cw1);
  // GEMM B: pw1b_v = proj_v @ w1b  (xb memory reused; 5 slabs x 75 = 375 blocks)
  gemm256<1><<<375, 512, 131072, stream>>>(projb, nullptr, nullptr, nullptr, w1bT,
                                           pw1b, nullptr, nullptr);
  // fused routing: 3 iterations pointwise in (b,n), no GEMMs (linearity of @w1b)
  k_iter3<<<BN_TOT, 192, 0, stream>>>(xw1b, cw1, pw1b, projb, b1, w2, outc, outr);
}